// Round 18
// baseline (283.909 us; speedup 1.0000x reference)
//
#include <hip/hip_runtime.h>

typedef float v4f __attribute__((ext_vector_type(4)));

#define NB   32     // batch
#define NT   8      // timesteps
#define NC   128    // channels
#define NQ   256    // float4s per (H*W)=1024 plane
#define CRED 32     // C/red
#define CPB  16     // channels per block

// Cross-block mean publish: each channel mean (double) is split into two
// 64-bit words:  word = (seq << 32) | 32-bit-half-of-double-bits, seq = t+1.
// Data and version share ONE atomic location -> freshness is self-validating
// (R0 lesson). One write-once slice PER STEP -> no WAR hazard -> no arrive
// barrier: consumers spin directly on the data words. Zeroed per launch so
// seq=0 is invalid across graph replays.
#define NWORDS (NT * NB * NC * 2)   // step x batch x channel x {lo,hi}

__device__ unsigned long long g_xw[NWORDS];          // (seq<<32 | half) words

__global__ __launch_bounds__(256)
void lif_init() {
    int i = threadIdx.x + blockIdx.x * blockDim.x;
    if (i < NWORDS) g_xw[i] = 0ull;
}

// Raw barrier: LDS-only drain (lgkmcnt), NO vmcnt(0). Keeps NT stores
// fire-and-forget and lets prefetch loads stay in flight across barriers.
#define LDS_BARRIER() asm volatile("s_waitcnt lgkmcnt(0)\n\ts_barrier" ::: "memory")

// ---------------------------------------------------------------------------
// R9: POLLERS NEVER STORE. R8 (fan-in 8, 89us = R3) showed waves 4-15's
// stores already drain off the wait path (their next wait is vmcnt(4) for
// loads, which are OLDER than their stores). The last store-drain on the
// critical chain: waves 0-3's poll -- its atomic load is the youngest VMEM
// op, so vmcnt(0) forces the pollers' own 16 KB of spike stores to ack
// (multi-us, R5/R7 evidence) before the poll can observe. Fix: sub-group 0
// computes spikes PRE-B1 into s_sp (LDS) + resets; after B1 its queue is
// {publish, 4 prefetch loads} only. Sub-group 1 reads s_sp after B1 and
// issues sub-0's spike stores with its own (stores on never-waited waves).
// Unlike R6: no duplicated HBM loads, one LDS buffer, parallel poll kept.
// s_sp WAR: read between B1/B2 of step t, overwritten after B3 -> safe.
// Spike values, publish bits, cc-ascending MLP, sigmoid unchanged ->
// outputs identical to the verified R3/R8 kernels.
// Co-residency: 256 blocks over 256 CUs, ~18 KB LDS, ~64 VGPR -> all
// resident; spin cannot deadlock. All barriers wave-uniform.
// ---------------------------------------------------------------------------
__global__ __launch_bounds__(1024, 4)
void dynamic_lif(const float* __restrict__ x,
                 const float* __restrict__ w1,
                 const float* __restrict__ b1,
                 const float* __restrict__ w2,
                 const float* __restrict__ b2,
                 float* __restrict__ out)
{
    const int bid = blockIdx.x;          // 0..255
    const int b   = bid >> 3;            // batch
    const int c0  = (bid & 7) << 4;      // first of 16 channels
    const int tid = threadIdx.x;         // 0..1023
    const int sub = tid >> 8;            // sub-group 0..3 (4 channels each)
    const int q   = tid & 255;           // v4f index within plane
    const int wig = (tid >> 6) & 3;      // wave index within sub-group
    const int ln  = tid & 63;

    __shared__ double       s_part[CPB][4];  // [channel][wave-in-group]
    __shared__ v4f          s_sp[4][256];    // sub-0 spike handoff (16 KB)
    __shared__ unsigned int s_w[256];        // fetched 32-bit halves
    __shared__ float        s_tau;

    const v4f* __restrict__ x4 = (const v4f*)x;
    v4f* __restrict__ o4       = (v4f*)out;

    // this thread's 4 channels: c0 + sub*4 + p
    const int cbase = c0 + (sub << 2);

    v4f mem[4];
    #pragma unroll
    for (int p = 0; p < 4; ++p) mem[p] = (v4f){0.f, 0.f, 0.f, 0.f};

    float tau = 0.5f;                    // TAU0

    v4f xv[4];
    #pragma unroll
    for (int p = 0; p < 4; ++p)
        xv[p] = __builtin_nontemporal_load(x4 + ((b * NT + 0) * NC + cbase + p) * NQ + q);

    for (int t = 0; t < NT; ++t) {
        // ---- phase A: fma + plane-sum ONLY; mem keeps PRE-reset values ----
        double psum[4];
        #pragma unroll
        for (int p = 0; p < 4; ++p) {
            v4f m = mem[p];
            m.x = fmaf(m.x, tau, xv[p].x);
            m.y = fmaf(m.y, tau, xv[p].y);
            m.z = fmaf(m.z, tau, xv[p].z);
            m.w = fmaf(m.w, tau, xv[p].w);
            psum[p] = ((double)m.x + (double)m.y) + ((double)m.z + (double)m.w);
            mem[p] = m;
        }

        #pragma unroll
        for (int p = 0; p < 4; ++p) {
            double s = psum[p];
            #pragma unroll
            for (int off = 32; off > 0; off >>= 1) s += __shfl_down(s, off);
            if (ln == 0) s_part[(sub << 2) + p][wig] = s;
        }

        // sub 0, non-last step: spikes -> LDS + reset BEFORE B1 (VALU+LDS
        // only). After B1 sub-0's VMEM queue stays {publish, prefetch}.
        if (t < NT - 1 && sub == 0) {
            #pragma unroll
            for (int p = 0; p < 4; ++p) {
                v4f m = mem[p];
                v4f sp;
                sp.x = (m.x > 1.0f) ? 1.0f : 0.0f;   // zif(mem-1): exact
                sp.y = (m.y > 1.0f) ? 1.0f : 0.0f;
                sp.z = (m.z > 1.0f) ? 1.0f : 0.0f;
                sp.w = (m.w > 1.0f) ? 1.0f : 0.0f;
                s_sp[p][q] = sp;
                m.x = (m.x > 1.0f) ? 0.0f : m.x;     // (1-spike)*mem
                m.y = (m.y > 1.0f) ? 0.0f : m.y;
                m.z = (m.z > 1.0f) ? 0.0f : m.z;
                m.w = (m.w > 1.0f) ? 0.0f : m.w;
                mem[p] = m;
            }
        }
        LDS_BARRIER();                   // B1: s_part + s_sp visible

        if (t == NT - 1) {
            // last step: nothing consumes the means; uniform direct stores
            #pragma unroll
            for (int p = 0; p < 4; ++p) {
                v4f m = mem[p];
                v4f sp;
                sp.x = (m.x > 1.0f) ? 1.0f : 0.0f;
                sp.y = (m.y > 1.0f) ? 1.0f : 0.0f;
                sp.z = (m.z > 1.0f) ? 1.0f : 0.0f;
                sp.w = (m.w > 1.0f) ? 1.0f : 0.0f;
                __builtin_nontemporal_store(sp,
                    o4 + ((b * NT + t) * NC + cbase + p) * NQ + q);
            }
            break;
        }

        if (sub == 0) {
            // ---- publish: FIRST VMEM ops of this step (lanes 0-15) ----
            if (tid < CPB) {
                double s = (s_part[tid][0] + s_part[tid][1]) +
                           (s_part[tid][2] + s_part[tid][3]);
                double mean = s * (1.0 / 1024.0);
                unsigned long long bits = __double_as_longlong(mean);
                unsigned long long tag  = ((unsigned long long)(t + 1)) << 32;
                const int base = ((t * NB + b) * NC + c0 + tid) * 2;
                __hip_atomic_store(&g_xw[base + 0], tag | (bits & 0xffffffffull),
                                   __ATOMIC_RELAXED, __HIP_MEMORY_SCOPE_AGENT);
                __hip_atomic_store(&g_xw[base + 1], tag | (bits >> 32),
                                   __ATOMIC_RELAXED, __HIP_MEMORY_SCOPE_AGENT);
            }
            // prefetch t+1 (these 4 loads are the only other queue entries)
            #pragma unroll
            for (int p = 0; p < 4; ++p)
                xv[p] = __builtin_nontemporal_load(
                    x4 + ((b * NT + (t + 1)) * NC + cbase + p) * NQ + q);

            // ---- seq-validated spin-fetch (256 lanes, 1 word each) ----
            // vmcnt(0) here drains only publish + prefetch: NO stores.
            {
                const int idx = (t * NB + b) * NC * 2 + tid;
                const unsigned int want = (unsigned int)(t + 1);
                unsigned long long w;
                for (;;) {
                    w = __hip_atomic_load(&g_xw[idx], __ATOMIC_RELAXED,
                                          __HIP_MEMORY_SCOPE_AGENT);
                    if ((unsigned int)(w >> 32) == want) break;
                    __builtin_amdgcn_s_sleep(1);
                }
                s_w[tid] = (unsigned int)w;
            }
        } else {
            // bulk waves: prefetch FIRST (loads older than stores -> next
            // phase A waits vmcnt(4), stores never on a wait path)
            #pragma unroll
            for (int p = 0; p < 4; ++p)
                xv[p] = __builtin_nontemporal_load(
                    x4 + ((b * NT + (t + 1)) * NC + cbase + p) * NQ + q);
            // own spike/store/reset
            #pragma unroll
            for (int p = 0; p < 4; ++p) {
                v4f m = mem[p];
                v4f sp;
                sp.x = (m.x > 1.0f) ? 1.0f : 0.0f;
                sp.y = (m.y > 1.0f) ? 1.0f : 0.0f;
                sp.z = (m.z > 1.0f) ? 1.0f : 0.0f;
                sp.w = (m.w > 1.0f) ? 1.0f : 0.0f;
                __builtin_nontemporal_store(sp,
                    o4 + ((b * NT + t) * NC + cbase + p) * NQ + q);
                m.x = (m.x > 1.0f) ? 0.0f : m.x;
                m.y = (m.y > 1.0f) ? 0.0f : m.y;
                m.z = (m.z > 1.0f) ? 0.0f : m.z;
                m.w = (m.w > 1.0f) ? 0.0f : m.w;
                mem[p] = m;
            }
            // sub 1 also stores sub-0's spikes from the LDS handoff
            if (sub == 1) {
                #pragma unroll
                for (int p = 0; p < 4; ++p) {
                    v4f sp0 = s_sp[p][q];
                    __builtin_nontemporal_store(sp0,
                        o4 + ((b * NT + t) * NC + c0 + p) * NQ + q);
                }
            }
        }

        LDS_BARRIER();                   // B2: s_w visible to wave 0

        // tiny MLP (128->32->1) on lanes 0-31 of wave 0; identical
        // cc-ascending order and exact double bits -> tau bit-identical.
        double e = 0.0;
        if (tid < CRED) {
            const v4f* __restrict__ w1v = (const v4f*)(w1 + tid * NC);
            double acc = (double)b1[tid];
            #pragma unroll
            for (int qq = 0; qq < NC / 4; ++qq) {
                v4f wq = w1v[qq];
                #pragma unroll
                for (int k = 0; k < 4; ++k) {
                    const int c = 4 * qq + k;
                    unsigned long long bits =
                        ((unsigned long long)s_w[2 * c + 1] << 32) | s_w[2 * c];
                    double xm = __longlong_as_double(bits);
                    acc += xm * (double)((k == 0) ? wq.x : (k == 1) ? wq.y
                                         : (k == 2) ? wq.z : wq.w);
                }
            }
            double emb = acc > 0.0 ? acc : 0.0;
            e = emb * (double)w2[tid];
        }
        #pragma unroll
        for (int off = 32; off > 0; off >>= 1) e += __shfl_down(e, off);
        if (tid == 0) {
            double z = e + (double)b2[0];
            s_tau = (float)(1.0 / (1.0 + exp(-z)));
        }
        LDS_BARRIER();                   // B3: s_tau visible to all 16 waves
        tau = s_tau;
    }
}

extern "C" void kernel_launch(void* const* d_in, const int* in_sizes, int n_in,
                              void* d_out, int out_size, void* d_ws, size_t ws_size,
                              hipStream_t stream) {
    const float* x  = (const float*)d_in[0];
    const float* w1 = (const float*)d_in[1];
    const float* b1 = (const float*)d_in[2];
    const float* w2 = (const float*)d_in[3];
    const float* b2 = (const float*)d_in[4];
    float* out      = (float*)d_out;

    // zero the seq-tagged word buffer (stream-ordered before the main kernel)
    hipLaunchKernelGGL(lif_init, dim3((NWORDS + 255) / 256), dim3(256),
                       0, stream);
    // plain launch — 256 blocks x 1024 threads (one per (batch, 16-channel
    // group)); no cooperative protocol overhead
    hipLaunchKernelGGL(dynamic_lif, dim3(NB * NC / CPB), dim3(1024), 0, stream,
                       x, w1, b1, w2, b2, out);
}